// Round 7
// baseline (246.287 us; speedup 1.0000x reference)
//
#include <hip/hip_runtime.h>
#include <math.h>
#include <float.h>

#define B_  4
#define L_  1024
#define N_  16384
#define D_  256
#define K_  5
#define NCH 32
#define CHUNK (N_/NCH)      // 512
#define RESC 16             // candidates rescored in fp32

typedef __attribute__((ext_vector_type(8))) short bf16x8;
typedef __attribute__((ext_vector_type(4))) float f32x4;

static __device__ __forceinline__ unsigned short f2bf(float f) {
    unsigned int u = __float_as_uint(f);
    unsigned int r = (u + 0x7FFFu + ((u >> 16) & 1u)) >> 16;
    return (unsigned short)r;
}

static __device__ __forceinline__ void gld16(const void* g, void* l) {
    __builtin_amdgcn_global_load_lds(
        (const __attribute__((address_space(1))) unsigned int*)g,
        (__attribute__((address_space(3))) unsigned int*)l, 16, 0, 0);
}

// ---------------- Kernel 1: inv norms + bf16 copies ----------------
__global__ __launch_bounds__(256) void prep_kernel(
    const float* __restrict__ enc, const float* __restrict__ mem,
    float* __restrict__ invn, unsigned short* __restrict__ memn_bf,
    unsigned short* __restrict__ enc_bf)
{
    const int row = blockIdx.x * 4 + (threadIdx.x >> 6);
    const int lane = threadIdx.x & 63;
    if (row < B_ * N_) {
        float4 v = reinterpret_cast<const float4*>(mem + (size_t)row * D_)[lane];
        float ss = v.x*v.x + v.y*v.y + v.z*v.z + v.w*v.w;
        #pragma unroll
        for (int off = 32; off; off >>= 1) ss += __shfl_xor(ss, off, 64);
        float inv = 1.0f / fmaxf(sqrtf(ss), 1e-12f);
        if (lane == 0) invn[row] = inv;
        uint2 p;
        p.x = (unsigned)f2bf(v.x*inv) | ((unsigned)f2bf(v.y*inv) << 16);
        p.y = (unsigned)f2bf(v.z*inv) | ((unsigned)f2bf(v.w*inv) << 16);
        reinterpret_cast<uint2*>(memn_bf + (size_t)row * D_)[lane] = p;
    } else {
        int r2 = row - B_ * N_;
        if (r2 >= B_ * L_) return;
        float4 v = reinterpret_cast<const float4*>(enc + (size_t)r2 * D_)[lane];
        uint2 p;
        p.x = (unsigned)f2bf(v.x) | ((unsigned)f2bf(v.y) << 16);
        p.y = (unsigned)f2bf(v.z) | ((unsigned)f2bf(v.w) << 16);
        reinterpret_cast<uint2*>(enc_bf + (size_t)r2 * D_)[lane] = p;
    }
}

// ---------------- Kernel 2: MFMA screen, 1024 blocks (4/CU) ----------------
// A = mem (n rows), B = enc (l rows), swapped-operand MFMA: per-lane l-column,
// n-candidates lane-local. Both tiles staged per k-step via global_load_lds
// (linear LDS dest + inverse-swizzled source; XOR on read).
// Key = (bits(max(s,0)) & 0xFFFFFC00) | (1023 - n_local). Branchless top-5.
__global__ __launch_bounds__(256, 4) void screen_kernel(
    const unsigned short* __restrict__ enc_bf,
    const unsigned short* __restrict__ memn_bf,
    unsigned int* __restrict__ pcand)
{
    __shared__ __align__(16) union {
        struct { unsigned char A[16*1024]; unsigned char B[16*1024]; } st; // 32 KB
        unsigned int mg[128][41];                                          // 21 KB
    } sm;

    const int tid = threadIdx.x;
    const int lane = tid & 63;
    const int wv = tid >> 6;
    const int wm = wv >> 1, wn = wv & 1;   // wm: n-halves, wn: l-halves
    const int b = blockIdx.z;
    const int l0 = blockIdx.y * 128;
    const int ch = blockIdx.x;

    const int ra = wm * 64 + (lane & 15);   // A(mem) frag row base (n-local)
    const int rb = wn * 64 + (lane & 15);   // B(enc) frag row base (l-local)
    const unsigned aswz = ((unsigned)(ra & 7)) << 4;
    const unsigned bswz = ((unsigned)(rb & 7)) << 4;
    const int kgB = (lane >> 4) * 16;       // byte offset of lane's k-group
    const int g4 = (lane >> 4) * 4;
    // staging: 8 rows/gld16, row = s*8 + (lane>>3); source col pre-swizzled
    const int srow = lane >> 3;             // 0..7  (== row & 7)
    const int scol = ((lane & 7) * 16) ^ (srow << 4);

    const char* encBb = (const char*)(enc_bf + ((size_t)b * L_ + l0) * D_);
    const char* memBb = (const char*)(memn_bf + ((size_t)b * N_ + ch * CHUNK) * D_);

    unsigned tl[4][5];   // 4 l-lists x sorted-desc top-5 packed keys
    #pragma unroll
    for (int j = 0; j < 4; ++j)
        #pragma unroll
        for (int p = 0; p < 5; ++p) tl[j][p] = 0u;

    for (int nt = 0; nt < CHUNK / 128; ++nt) {     // 4 n-tiles
        const int n0 = nt * 128;
        f32x4 acc[4][4];
        #pragma unroll
        for (int i = 0; i < 4; ++i)
            #pragma unroll
            for (int j = 0; j < 4; ++j) acc[i][j] = (f32x4){0.f,0.f,0.f,0.f};

        #pragma unroll
        for (int kt = 0; kt < 4; ++kt) {           // 64-k steps
            __syncthreads();
            #pragma unroll
            for (int c = 0; c < 4; ++c) {
                const int s = c * 4 + wv;
                gld16(encBb + (size_t)(s * 8 + srow) * 512 + kt * 128 + scol,
                      sm.st.B + s * 1024);
                gld16(memBb + (size_t)(n0 + s * 8 + srow) * 512 + kt * 128 + scol,
                      sm.st.A + s * 1024);
            }
            __syncthreads();
            #pragma unroll
            for (int kk = 0; kk < 2; ++kk) {
                const int kb = kk * 64 + kgB;
                bf16x8 af[4], bfv[4];
                #pragma unroll
                for (int m = 0; m < 4; ++m)
                    af[m] = *reinterpret_cast<const bf16x8*>(
                        sm.st.A + (ra + m * 16) * 128 + (kb ^ aswz));
                #pragma unroll
                for (int n = 0; n < 4; ++n)
                    bfv[n] = *reinterpret_cast<const bf16x8*>(
                        sm.st.B + (rb + n * 16) * 128 + (kb ^ bswz));
                #pragma unroll
                for (int m = 0; m < 4; ++m)
                    #pragma unroll
                    for (int n = 0; n < 4; ++n)
                        acc[m][n] = __builtin_amdgcn_mfma_f32_16x16x32_bf16(
                            af[m], bfv[n], acc[m][n], 0, 0, 0);
            }
        }

        // branchless fold: 64 scores/lane -> 4 per-lane top-5 lists
        #pragma unroll
        for (int i = 0; i < 4; ++i) {
            #pragma unroll
            for (int r = 0; r < 4; ++r) {
                const unsigned idxv = 1023u - (unsigned)(n0 + wm * 64 + i * 16 + g4 + r);
                #pragma unroll
                for (int j = 0; j < 4; ++j) {      // j innermost: 4-way ILP
                    unsigned c2 = (__float_as_uint(fmaxf(acc[i][j][r], 0.0f))
                                   & 0xFFFFFC00u) | idxv;
                    #pragma unroll
                    for (int p = 0; p < 5; ++p) {
                        unsigned mx = tl[j][p] > c2 ? tl[j][p] : c2;
                        unsigned mn = tl[j][p] > c2 ? c2 : tl[j][p];
                        tl[j][p] = mx; c2 = mn;
                    }
                }
            }
        }
    }

    __syncthreads();   // staging LDS dead; reuse as merge buffer
    {
        const int c = lane & 15;
        const int src = wm * 4 + (lane >> 4);      // 0..7
        #pragma unroll
        for (int j = 0; j < 4; ++j) {
            const int l = wn * 64 + j * 16 + c;
            #pragma unroll
            for (int p = 0; p < 5; ++p)
                sm.mg[l][src * 5 + p] = tl[j][p];
        }
    }
    __syncthreads();

    if (tid < 128) {
        unsigned best[8];
        #pragma unroll
        for (int p = 0; p < 8; ++p) best[p] = 0u;
        #pragma unroll
        for (int c = 0; c < 40; ++c) {
            unsigned key = sm.mg[tid][c];
            #pragma unroll
            for (int p = 0; p < 8; ++p) {
                unsigned mx = best[p] > key ? best[p] : key;
                unsigned mn = best[p] > key ? key : best[p];
                best[p] = mx; key = mn;
            }
        }
        size_t gb = (((size_t)b * L_ + l0 + tid) * NCH + ch) * 8;
        #pragma unroll
        for (int p = 0; p < 8; ++p) pcand[gb + p] = best[p];
    }
}

// ---------------- Kernel 3: radix-select top-16 of 256, fp32 rescore,
//                  top-5, gather+mean, fused linear ----------------
__global__ __launch_bounds__(256) void tail_kernel(
    const float* __restrict__ enc, const float* __restrict__ mem,
    const float* __restrict__ invn,
    const unsigned int* __restrict__ pcand,
    const float* __restrict__ W, const float* __restrict__ bias,
    float* __restrict__ out)
{
    __shared__ float t_s[8][D_];
    __shared__ int cand_s[4][RESC];
    const int wv = threadIdx.x >> 6;
    const int lane = threadIdx.x & 63;
    const int row0 = blockIdx.x * 8 + wv * 2;

    #pragma unroll 1
    for (int r2 = 0; r2 < 2; ++r2) {
        const int row = row0 + r2;
        const int b = row >> 10;
        const int l = row & 1023;

        const size_t cb = (size_t)row * (NCH * 8);
        unsigned k0 = pcand[cb + lane],       k1 = pcand[cb + 64 + lane];
        unsigned k2 = pcand[cb + 128 + lane], k3 = pcand[cb + 192 + lane];

        // radix-select: v = 16th largest of the 256 keys (exact, dup-safe)
        unsigned v = 0;
        #pragma unroll
        for (int bit = 31; bit >= 0; --bit) {
            unsigned t = v | (1u << bit);
            int c = __popcll(__ballot(k0 >= t)) + __popcll(__ballot(k1 >= t))
                  + __popcll(__ballot(k2 >= t)) + __popcll(__ballot(k3 >= t));
            v = (c >= RESC) ? t : v;
        }
        unsigned long long a0 = __ballot(k0 > v), a1 = __ballot(k1 > v);
        unsigned long long a2 = __ballot(k2 > v), a3 = __ballot(k3 > v);
        unsigned long long e0 = __ballot(k0 == v), e1 = __ballot(k1 == v);
        unsigned long long e2 = __ballot(k2 == v), e3 = __ballot(k3 == v);
        const int nA0 = __popcll(a0), nA1 = __popcll(a1), nA2 = __popcll(a2);
        const int nA = nA0 + nA1 + nA2 + __popcll(a3);
        const int ne0 = __popcll(e0), ne1 = __popcll(e1), ne2 = __popcll(e2);
        const int need = RESC - nA;
        const unsigned long long lt = (1ull << lane) - 1ull;
        int s0 = -1, s1 = -1, s2 = -1, s3 = -1;
        if (k0 > v) s0 = __popcll(a0 & lt);
        else if (k0 == v) { int r = __popcll(e0 & lt); if (r < need) s0 = nA + r; }
        if (k1 > v) s1 = nA0 + __popcll(a1 & lt);
        else if (k1 == v) { int r = ne0 + __popcll(e1 & lt); if (r < need) s1 = nA + r; }
        if (k2 > v) s2 = nA0 + nA1 + __popcll(a2 & lt);
        else if (k2 == v) { int r = ne0 + ne1 + __popcll(e2 & lt); if (r < need) s2 = nA + r; }
        if (k3 > v) s3 = nA0 + nA1 + nA2 + __popcll(a3 & lt);
        else if (k3 == v) { int r = ne0 + ne1 + ne2 + __popcll(e3 & lt); if (r < need) s3 = nA + r; }
        if (s0 >= 0) cand_s[wv][s0] = ((lane) >> 3) * CHUNK + 1023 - (int)(k0 & 1023u);
        if (s1 >= 0) cand_s[wv][s1] = ((64 + lane) >> 3) * CHUNK + 1023 - (int)(k1 & 1023u);
        if (s2 >= 0) cand_s[wv][s2] = ((128 + lane) >> 3) * CHUNK + 1023 - (int)(k2 & 1023u);
        if (s3 >= 0) cand_s[wv][s3] = ((192 + lane) >> 3) * CHUNK + 1023 - (int)(k3 & 1023u);
        asm volatile("s_waitcnt lgkmcnt(0)" ::: "memory");

        // fp32 rescore: lane -> candidate lane>>2, quarter lane&3
        const int ci = cand_s[wv][lane >> 2];
        const int q = lane & 3;
        const float4* er = reinterpret_cast<const float4*>(enc + ((size_t)b * L_ + l) * D_) + q * 16;
        const float4* mr = reinterpret_cast<const float4*>(mem + ((size_t)b * N_ + ci) * D_) + q * 16;
        float s = 0.0f;
        #pragma unroll
        for (int k = 0; k < 16; ++k) {
            float4 e = er[k], m = mr[k];
            s = fmaf(e.x, m.x, s); s = fmaf(e.y, m.y, s);
            s = fmaf(e.z, m.z, s); s = fmaf(e.w, m.w, s);
        }
        s += __shfl_xor(s, 1, 64);
        s += __shfl_xor(s, 2, 64);
        s *= invn[b * N_ + ci];

        float sw = s;
        int m0, m1, m2, m3, m4;
        #define PICK(MK) { \
            float mv = sw; int mi = ci; \
            if (sw == -FLT_MAX) mi = 0x7fffffff; \
            _Pragma("unroll") \
            for (int off = 32; off >= 4; off >>= 1) { \
                float ov = __shfl_xor(mv, off, 64); \
                int oi = __shfl_xor(mi, off, 64); \
                if (ov > mv || (ov == mv && oi < mi)) { mv = ov; mi = oi; } \
            } \
            MK = mi; \
            if (ci == mi) sw = -FLT_MAX; \
        }
        PICK(m0); PICK(m1); PICK(m2); PICK(m3); PICK(m4);
        #undef PICK

        const float4* eb = reinterpret_cast<const float4*>(enc + ((size_t)b * L_ + l) * D_);
        const float4* mb = reinterpret_cast<const float4*>(mem + (size_t)b * N_ * D_);
        float4 e = eb[lane];
        float4 g0 = mb[(size_t)m0 * 64 + lane];
        float4 g1 = mb[(size_t)m1 * 64 + lane];
        float4 g2 = mb[(size_t)m2 * 64 + lane];
        float4 g3 = mb[(size_t)m3 * 64 + lane];
        float4 g4v = mb[(size_t)m4 * 64 + lane];
        float4 o;
        o.x = e.x + 0.2f * (g0.x + g1.x + g2.x + g3.x + g4v.x);
        o.y = e.y + 0.2f * (g0.y + g1.y + g2.y + g3.y + g4v.y);
        o.z = e.z + 0.2f * (g0.z + g1.z + g2.z + g3.z + g4v.z);
        o.w = e.w + 0.2f * (g0.w + g1.w + g2.w + g3.w + g4v.w);
        *reinterpret_cast<float4*>(&t_s[wv * 2 + r2][lane * 4]) = o;
    }
    __syncthreads();

    // linear: thread = dout for all 8 rows
    const int dout = threadIdx.x;
    float accr[8];
    #pragma unroll
    for (int r = 0; r < 8; ++r) accr[r] = 0.0f;
    const float4* Wr = reinterpret_cast<const float4*>(W + (size_t)dout * D_);
    for (int d4 = 0; d4 < D_ / 4; ++d4) {
        float4 w = Wr[d4];
        #pragma unroll
        for (int r = 0; r < 8; ++r) {
            float4 t = *reinterpret_cast<const float4*>(&t_s[r][d4 * 4]);
            accr[r] = fmaf(w.x, t.x, accr[r]);
            accr[r] = fmaf(w.y, t.y, accr[r]);
            accr[r] = fmaf(w.z, t.z, accr[r]);
            accr[r] = fmaf(w.w, t.w, accr[r]);
        }
    }
    float bb = bias[dout];
    #pragma unroll
    for (int r = 0; r < 8; ++r)
        out[((size_t)blockIdx.x * 8 + r) * D_ + dout] = accr[r] + bb;
}

extern "C" void kernel_launch(void* const* d_in, const int* in_sizes, int n_in,
                              void* d_out, int out_size, void* d_ws, size_t ws_size,
                              hipStream_t stream)
{
    (void)in_sizes; (void)n_in; (void)out_size;
    const float* enc  = (const float*)d_in[0];
    const float* mem  = (const float*)d_in[1];
    const float* W    = (const float*)d_in[2];
    const float* bias = (const float*)d_in[3];
    float* out = (float*)d_out;

    const size_t sz_memn = (size_t)B_ * N_ * D_ * 2;        // 32 MiB
    const size_t sz_enc  = (size_t)B_ * L_ * D_ * 2;        // 2 MiB
    const size_t sz_invn = (size_t)B_ * N_ * 4;             // 256 KiB
    const size_t sz_pc   = (size_t)B_ * L_ * NCH * 8 * 4;   // 4 MiB
    const size_t need = sz_memn + sz_enc + sz_invn + sz_pc;
    if (ws_size < need) return;

    char* p = (char*)d_ws;
    unsigned short* memn_bf = (unsigned short*)p;  p += sz_memn;
    unsigned short* enc_bf  = (unsigned short*)p;  p += sz_enc;
    float* invn = (float*)p;  p += sz_invn;
    unsigned int* pcand = (unsigned int*)p;

    {
        int rows = B_ * N_ + B_ * L_;
        prep_kernel<<<(rows + 3) / 4, 256, 0, stream>>>(enc, mem, invn, memn_bf, enc_bf);
    }
    {
        dim3 grid(NCH, L_ / 128, B_);
        screen_kernel<<<grid, 256, 0, stream>>>(enc_bf, memn_bf, pcand);
    }
    {
        tail_kernel<<<(B_ * L_) / 8, 256, 0, stream>>>(enc, mem, invn, pcand, W, bias, out);
    }
}